// Round 1
// 288.907 us; speedup vs baseline: 1.0579x; 1.0579x over previous
//
#include <hip/hip_runtime.h>

// out[b, i*16+j, d, l] = sum_ks s[b,(j-i)&15,l,ks] * t[b,j,l,d-ks], d in [0,125); 0 for d>=125.
// B=32, N=16, L=64, D_in=63, D_out=128. Output 32*256*128*64 fp32 = 256 MB.
//
// v2: two-dispatch pipeline.
//   1) transpose_kernel: s,t [B,N,L,63] -> [B,N,63,L] in d_ws (~33 MB traffic, ~10us).
//      Reason: conv lanes are indexed by l, so row-major [L,63] input makes every
//      input load a 64-line gather (~8K L1 transactions/wave ~= the FMA work).
//      Transposed layout makes all 126 input loads per wave fully coalesced (256B).
//   2) conv_kernel_t: identical FMA structure to v1 (63*63 = 3969 v_fma_f32/lane,
//      16 independent accumulators per d-chunk), coalesced loads, nontemporal
//      stores (output is write-once, 268 MB -- keep it out of L2).
// Fallback to the v1 uncoalesced kernel if ws_size < 16.5 MB.

#define D_IN 63
#define L_DIM 64
#define N_DIM 16
#define DP 128
#define B_DIM 32

// ---------- transpose [B,N,L,D_IN] -> [B,N,D_IN,L] ----------
__global__ __launch_bounds__(256) void transpose_kernel(
    const float* __restrict__ s, const float* __restrict__ t,
    float* __restrict__ so, float* __restrict__ to)
{
    const int tile = blockIdx.x;                     // 0..1023 ; first 512 = s, rest = t
    const int bn   = tile & (B_DIM * N_DIM - 1);     // 0..511
    const float* __restrict__ src =
        (tile < B_DIM * N_DIM ? s : t) + (size_t)bn * (L_DIM * D_IN);
    float* __restrict__ dst =
        (tile < B_DIM * N_DIM ? so : to) + (size_t)bn * (L_DIM * D_IN);

    __shared__ float lds[L_DIM * D_IN];              // 16128 B

    // coalesced read of the [L,D] tile
    for (int f = threadIdx.x; f < L_DIM * D_IN; f += 256)
        lds[f] = src[f];
    __syncthreads();

    // coalesced write of the [D,L] tile; lds read is stride-63 across lanes
    // (63 mod 32 = 31 -> conflict-free)
    for (int g = threadIdx.x; g < L_DIM * D_IN; g += 256) {
        const int d = g >> 6;        // 0..62
        const int l = g & 63;
        dst[g] = lds[l * D_IN + d];
    }
}

// ---------- conv on transposed inputs ----------
__global__ __launch_bounds__(64) void conv_kernel_t(
    const float* __restrict__ st, const float* __restrict__ tt,
    float* __restrict__ out)
{
    const int blk = blockIdx.x;          // b*256 + i*16 + j
    const int b  = blk >> 8;
    const int ij = blk & 255;
    const int i  = ij >> 4;
    const int j  = ij & 15;
    const int k  = (j - i) & 15;
    const int l  = threadIdx.x;          // 0..63

    // transposed layout: element (b,n,c,l) at ((b*16+n)*63 + c)*64 + l
    const float* __restrict__ srow = st + (((size_t)b * N_DIM + k) * D_IN) * L_DIM + l;
    const float* __restrict__ trow = tt + (((size_t)b * N_DIM + j) * D_IN) * L_DIM + l;

    float sv[D_IN], tv[D_IN];
#pragma unroll
    for (int c = 0; c < D_IN; ++c) sv[c] = srow[(size_t)c * L_DIM];  // coalesced
#pragma unroll
    for (int c = 0; c < D_IN; ++c) tv[c] = trow[(size_t)c * L_DIM];  // coalesced

    float* __restrict__ orow = out + ((size_t)blk * (DP * L_DIM)) + l;

#pragma unroll
    for (int d0 = 0; d0 < DP; d0 += 16) {
        float acc[16];
#pragma unroll
        for (int dd = 0; dd < 16; ++dd) acc[dd] = 0.0f;

#pragma unroll
        for (int ks = 0; ks < D_IN; ++ks) {
#pragma unroll
            for (int dd = 0; dd < 16; ++dd) {
                const int kt = d0 + dd - ks;           // compile-time constant
                if (kt >= 0 && kt < D_IN)
                    acc[dd] += sv[ks] * tv[kt];
            }
        }

#pragma unroll
        for (int dd = 0; dd < 16; ++dd)
            __builtin_nontemporal_store(acc[dd], orow + (size_t)(d0 + dd) * L_DIM);
    }
}

// ---------- v1 fallback (uncoalesced loads) ----------
__global__ __launch_bounds__(64) void conv_kernel_fallback(
    const float* __restrict__ s, const float* __restrict__ t,
    float* __restrict__ out)
{
    const int blk = blockIdx.x;
    const int b  = blk >> 8;
    const int ij = blk & 255;
    const int i  = ij >> 4;
    const int j  = ij & 15;
    const int k  = (j - i) & 15;
    const int l  = threadIdx.x;

    const float* __restrict__ srow = s + ((((size_t)b * N_DIM + k) * L_DIM + l) * D_IN);
    const float* __restrict__ trow = t + ((((size_t)b * N_DIM + j) * L_DIM + l) * D_IN);

    float sv[D_IN], tv[D_IN];
#pragma unroll
    for (int c = 0; c < D_IN; ++c) sv[c] = srow[c];
#pragma unroll
    for (int c = 0; c < D_IN; ++c) tv[c] = trow[c];

    float* __restrict__ orow = out + ((size_t)blk * (DP * L_DIM)) + l;

#pragma unroll
    for (int d0 = 0; d0 < DP; d0 += 16) {
        float acc[16];
#pragma unroll
        for (int dd = 0; dd < 16; ++dd) acc[dd] = 0.0f;
#pragma unroll
        for (int ks = 0; ks < D_IN; ++ks) {
#pragma unroll
            for (int dd = 0; dd < 16; ++dd) {
                const int kt = d0 + dd - ks;
                if (kt >= 0 && kt < D_IN)
                    acc[dd] += sv[ks] * tv[kt];
            }
        }
#pragma unroll
        for (int dd = 0; dd < 16; ++dd)
            orow[(size_t)(d0 + dd) * L_DIM] = acc[dd];
    }
}

extern "C" void kernel_launch(void* const* d_in, const int* in_sizes, int n_in,
                              void* d_out, int out_size, void* d_ws, size_t ws_size,
                              hipStream_t stream) {
    const float* s = (const float*)d_in[0];
    const float* t = (const float*)d_in[1];
    float* out = (float*)d_out;

    const size_t elems = (size_t)B_DIM * N_DIM * L_DIM * D_IN;   // 2,064,384
    const size_t need  = 2 * elems * sizeof(float);              // ~16.5 MB

    if (d_ws != nullptr && ws_size >= need) {
        float* so = (float*)d_ws;
        float* to = so + elems;
        hipLaunchKernelGGL(transpose_kernel, dim3(2 * B_DIM * N_DIM), dim3(256), 0, stream,
                           s, t, so, to);
        hipLaunchKernelGGL(conv_kernel_t, dim3(B_DIM * N_DIM * N_DIM), dim3(64), 0, stream,
                           so, to, out);
    } else {
        hipLaunchKernelGGL(conv_kernel_fallback, dim3(B_DIM * N_DIM * N_DIM), dim3(64), 0, stream,
                           s, t, out);
    }
}